// Round 1
// baseline (1310.859 us; speedup 1.0000x reference)
//
#include <hip/hip_runtime.h>
#include <hip/hip_bf16.h>
#include <math.h>

#define B_  32
#define LQ_ 1024
#define LK_ 1024
#define D_  256

#define QB  32
#define KB  16
#define LDQ 260   // D_ + 4 pad (keeps f4 alignment, breaks power-of-2 bank stride)
#define LDK 260
#define LDP 20    // KB + 4 pad

// ---------------------------------------------------------------------------
// Projection GEMM: C[M,256] = A[M,256] @ W[256,256], fp32 vector FMA.
// BM=BN=64, BK=16, 256 threads, 4x4 per thread. blockIdx.z picks Q/K/V.
// ---------------------------------------------------------------------------
__global__ __launch_bounds__(256) void proj_gemm_kernel(
    const float* __restrict__ A0, const float* __restrict__ W0,
    const float* __restrict__ A1, const float* __restrict__ W1,
    const float* __restrict__ A2, const float* __restrict__ W2,
    float* __restrict__ C0, float* __restrict__ C1, float* __restrict__ C2)
{
    const int z = blockIdx.z;
    const float* __restrict__ A = (z == 0) ? A0 : (z == 1) ? A1 : A2;
    const float* __restrict__ W = (z == 0) ? W0 : (z == 1) ? W1 : W2;
    float* __restrict__ C       = (z == 0) ? C0 : (z == 1) ? C1 : C2;

    __shared__ float As[16][68];   // As[k][m], pad 68 -> 2-way max (free)
    __shared__ float Ws[16][68];   // Ws[k][n]

    const int bm = blockIdx.x * 64;
    const int bn = blockIdx.y * 64;
    const int t  = threadIdx.x;
    const int ty = t >> 4, tx = t & 15;

    float acc[4][4] = {};

    for (int k0 = 0; k0 < 256; k0 += 16) {
        {
            // A tile 64x16: one float4 per thread, stored transposed
            int r  = t >> 2, cs = (t & 3) << 2;
            float4 a4 = *(const float4*)(A + (size_t)(bm + r) * 256 + k0 + cs);
            As[cs + 0][r] = a4.x;
            As[cs + 1][r] = a4.y;
            As[cs + 2][r] = a4.z;
            As[cs + 3][r] = a4.w;
            // W tile 16x64: one float4 per thread
            int kr = t >> 4, js = (t & 15) << 2;
            *(float4*)&Ws[kr][js] = *(const float4*)(W + (size_t)(k0 + kr) * 256 + bn + js);
        }
        __syncthreads();
        #pragma unroll
        for (int k = 0; k < 16; ++k) {
            float4 a4 = *(float4*)&As[k][ty << 2];
            float4 b4 = *(float4*)&Ws[k][tx << 2];
            float av[4] = {a4.x, a4.y, a4.z, a4.w};
            float bv[4] = {b4.x, b4.y, b4.z, b4.w};
            #pragma unroll
            for (int i = 0; i < 4; ++i)
                #pragma unroll
                for (int j = 0; j < 4; ++j)
                    acc[i][j] = fmaf(av[i], bv[j], acc[i][j]);
        }
        __syncthreads();
    }

    #pragma unroll
    for (int i = 0; i < 4; ++i) {
        float4 w = make_float4(acc[i][0], acc[i][1], acc[i][2], acc[i][3]);
        *(float4*)(C + (size_t)(bm + (ty << 2) + i) * 256 + bn + (tx << 2)) = w;
    }
}

// ---------------------------------------------------------------------------
// Flash attention, fp32. One block per (q-tile of 32 rows, batch).
// 256 threads = 4 waves. K and V time-share one 16x256 LDS buffer.
// Row ownership for softmax/PV/output: row r = t>>3, 8 threads per row,
// thread owns columns (t&7)*4 + 32*jj, jj=0..7 (strided -> conflict-free V).
// ---------------------------------------------------------------------------
__global__ __launch_bounds__(256) void flash_kernel(
    const float* __restrict__ Q, const float* __restrict__ K,
    const float* __restrict__ V, const int* __restrict__ mask,
    float* __restrict__ Out)
{
    __shared__ float Qs[QB][LDQ];
    __shared__ float KVs[KB][LDK];
    __shared__ float Ps[QB][LDP];

    const int b  = blockIdx.y;
    const int q0 = blockIdx.x * QB;
    const int t  = threadIdx.x;

    const float* __restrict__ Qb = Q + ((size_t)b * LQ_ + q0) * D_;
    const float* __restrict__ Kb = K + (size_t)b * LK_ * D_;
    const float* __restrict__ Vb = V + (size_t)b * LK_ * D_;

    // stage Q tile (32x256) once: 2048 float4, 8 per thread
    #pragma unroll
    for (int i = 0; i < 8; ++i) {
        int idx = t + (i << 8);
        int r   = idx >> 6;
        int c   = (idx & 63) << 2;
        *(float4*)&Qs[r][c] = *(const float4*)(Qb + r * D_ + c);
    }

    const int r  = t >> 3;   // row owned for softmax / PV / output
    const int lc = t & 7;
    const int ty = t >> 4;   // S-phase: rows 2ty, 2ty+1
    const int tx = t & 15;   // S-phase: col tx
    const int qr = ty << 1;

    const int mv = mask[(size_t)b * LQ_ + q0 + r];

    float4 o4[8];
    #pragma unroll
    for (int i = 0; i < 8; ++i) o4[i] = make_float4(0.f, 0.f, 0.f, 0.f);
    float m_r = -INFINITY, l_r = 0.f;

    for (int kt = 0; kt < LK_ / KB; ++kt) {
        const float* Kt = Kb + (size_t)(kt * KB) * D_;
        const float* Vt = Vb + (size_t)(kt * KB) * D_;

        __syncthreads();   // previous PV finished reading KVs
        // stage K tile (16x256): 1024 float4, 4 per thread
        #pragma unroll
        for (int i = 0; i < 4; ++i) {
            int idx = t + (i << 8);
            int rr  = idx >> 6;
            int c   = (idx & 63) << 2;
            *(float4*)&KVs[rr][c] = *(const float4*)(Kt + rr * D_ + c);
        }
        __syncthreads();

        // S = Q K^T for this tile: each thread 2 rows x 1 col, f4 over d
        float s0 = 0.f, s1 = 0.f;
        #pragma unroll 16
        for (int d4 = 0; d4 < 64; ++d4) {
            float4 kv = *(float4*)&KVs[tx][d4 << 2];
            float4 qa = *(float4*)&Qs[qr][d4 << 2];
            float4 qb = *(float4*)&Qs[qr + 1][d4 << 2];
            s0 = fmaf(qa.x, kv.x, s0); s0 = fmaf(qa.y, kv.y, s0);
            s0 = fmaf(qa.z, kv.z, s0); s0 = fmaf(qa.w, kv.w, s0);
            s1 = fmaf(qb.x, kv.x, s1); s1 = fmaf(qb.y, kv.y, s1);
            s1 = fmaf(qb.z, kv.z, s1); s1 = fmaf(qb.w, kv.w, s1);
        }
        Ps[qr][tx]     = s0;
        Ps[qr + 1][tx] = s1;
        __syncthreads();   // S visible to row owners; KVs reads done

        // softmax update (8 threads per row, 2 cols each) + stage V
        {
            float2 sv = *(float2*)&Ps[r][lc << 1];
            if (!mv) { sv.x = 0.f; sv.y = 0.f; }   // masked row -> scores zeroed
            float lm = fmaxf(sv.x, sv.y);
            lm = fmaxf(lm, __shfl_xor(lm, 1));
            lm = fmaxf(lm, __shfl_xor(lm, 2));
            lm = fmaxf(lm, __shfl_xor(lm, 4));
            float m_new = fmaxf(m_r, lm);
            float scale = __expf(m_r - m_new);     // exp(-inf)=0 on first tile
            float p0 = __expf(sv.x - m_new);
            float p1 = __expf(sv.y - m_new);
            float2 pv2 = make_float2(p0, p1);
            *(float2*)&Ps[r][lc << 1] = pv2;
            float ls = p0 + p1;
            ls += __shfl_xor(ls, 1);
            ls += __shfl_xor(ls, 2);
            ls += __shfl_xor(ls, 4);
            l_r = l_r * scale + ls;
            m_r = m_new;
            #pragma unroll
            for (int jj = 0; jj < 8; ++jj) {
                o4[jj].x *= scale; o4[jj].y *= scale;
                o4[jj].z *= scale; o4[jj].w *= scale;
            }
        }
        // stage V into same buffer (all S reads of K done at previous barrier)
        #pragma unroll
        for (int i = 0; i < 4; ++i) {
            int idx = t + (i << 8);
            int rr  = idx >> 6;
            int c   = (idx & 63) << 2;
            *(float4*)&KVs[rr][c] = *(const float4*)(Vt + rr * D_ + c);
        }
        __syncthreads();

        // PV: o[r, lc*4 + 32*jj] += p[r,k] * V[k, ...]
        #pragma unroll 4
        for (int k = 0; k < KB; ++k) {
            float p = Ps[r][k];
            #pragma unroll
            for (int jj = 0; jj < 8; ++jj) {
                float4 v = *(float4*)&KVs[k][(lc << 2) + (jj << 5)];
                o4[jj].x = fmaf(p, v.x, o4[jj].x);
                o4[jj].y = fmaf(p, v.y, o4[jj].y);
                o4[jj].z = fmaf(p, v.z, o4[jj].z);
                o4[jj].w = fmaf(p, v.w, o4[jj].w);
            }
        }
    }

    // epilogue: out = o / l
    float inv = 1.0f / l_r;
    float* op = Out + ((size_t)b * LQ_ + q0 + r) * D_ + (lc << 2);
    #pragma unroll
    for (int jj = 0; jj < 8; ++jj) {
        float4 w = o4[jj];
        w.x *= inv; w.y *= inv; w.z *= inv; w.w *= inv;
        *(float4*)(op + (jj << 5)) = w;
    }
}

extern "C" void kernel_launch(void* const* d_in, const int* in_sizes, int n_in,
                              void* d_out, int out_size, void* d_ws, size_t ws_size,
                              hipStream_t stream) {
    const float* rq = (const float*)d_in[0];
    const float* rk = (const float*)d_in[1];
    const float* rv = (const float*)d_in[2];
    const int*   vm = (const int*)d_in[3];
    const float* WQ = (const float*)d_in[4];
    const float* WK = (const float*)d_in[5];
    const float* WV = (const float*)d_in[6];
    float* out = (float*)d_out;

    float* Qp = (float*)d_ws;                      // 32 MB
    float* Kp = Qp + (size_t)B_ * LQ_ * D_;        // 32 MB
    float* Vp = Kp + (size_t)B_ * LK_ * D_;        // 32 MB

    dim3 pg(512, 4, 3);    // (32768/64, 256/64, {Q,K,V})
    proj_gemm_kernel<<<pg, 256, 0, stream>>>(rq, WQ, rk, WK, rv, WV, Qp, Kp, Vp);

    dim3 fg(LQ_ / QB, B_); // (32, 32)
    flash_kernel<<<fg, 256, 0, stream>>>(Qp, Kp, Vp, vm, out);
}

// Round 2
// 262.144 us; speedup vs baseline: 5.0005x; 5.0005x over previous
//
#include <hip/hip_runtime.h>
#include <hip/hip_bf16.h>
#include <math.h>

#define B_ 32
#define L_ 1024
#define D_ 256

typedef _Float16 half8 __attribute__((ext_vector_type(8)));
typedef short    s16x8 __attribute__((ext_vector_type(8)));
typedef float    f32x4 __attribute__((ext_vector_type(4)));

typedef __attribute__((address_space(3))) unsigned int lds_u32;
typedef __attribute__((address_space(1))) unsigned int gbl_u32;

__device__ __forceinline__ void gl_lds16(const void* g, void* l) {
    __builtin_amdgcn_global_load_lds((gbl_u32*)g, (lds_u32*)l, 16, 0, 0);
}

__device__ __forceinline__ unsigned short f2bf(float x) {
    unsigned u = __float_as_uint(x);
    u += 0x7FFFu + ((u >> 16) & 1u);
    return (unsigned short)(u >> 16);
}

__device__ __forceinline__ unsigned short f2h(float x) {
    _Float16 h = (_Float16)x;
    unsigned short u;
    __builtin_memcpy(&u, &h, 2);
    return u;
}

// ---------------------------------------------------------------------------
// Projection GEMM (fp32 vector FMA, exact-ish): C = A[M,256] @ W[256,256].
// z=0 -> Qh fp16 row-major; z=1 -> Kh fp16 row-major;
// z=2 -> Vt bf16 TRANSPOSED per batch: Vt[b][d][k] (via LDS transpose).
// ---------------------------------------------------------------------------
__global__ __launch_bounds__(256) void proj_kernel(
    const float* __restrict__ A0, const float* __restrict__ W0,
    const float* __restrict__ A1, const float* __restrict__ W1,
    const float* __restrict__ A2, const float* __restrict__ W2,
    unsigned short* __restrict__ Qh, unsigned short* __restrict__ Kh,
    unsigned short* __restrict__ Vt)
{
    const int z = blockIdx.z;
    const float* __restrict__ A = (z == 0) ? A0 : (z == 1) ? A1 : A2;
    const float* __restrict__ W = (z == 0) ? W0 : (z == 1) ? W1 : W2;

    __shared__ float As[16][68];
    __shared__ float Ws[16][68];
    __shared__ unsigned short Tt[64][80];   // V transpose staging

    const int bm = blockIdx.x * 64;
    const int bn = blockIdx.y * 64;
    const int t  = threadIdx.x;
    const int ty = t >> 4, tx = t & 15;

    float acc[4][4] = {};

    for (int k0 = 0; k0 < 256; k0 += 16) {
        {
            int r  = t >> 2, cs = (t & 3) << 2;
            float4 a4 = *(const float4*)(A + (size_t)(bm + r) * 256 + k0 + cs);
            As[cs + 0][r] = a4.x;
            As[cs + 1][r] = a4.y;
            As[cs + 2][r] = a4.z;
            As[cs + 3][r] = a4.w;
            int kr = t >> 4, js = (t & 15) << 2;
            *(float4*)&Ws[kr][js] = *(const float4*)(W + (size_t)(k0 + kr) * 256 + bn + js);
        }
        __syncthreads();
        #pragma unroll
        for (int k = 0; k < 16; ++k) {
            float4 a4 = *(float4*)&As[k][ty << 2];
            float4 b4 = *(float4*)&Ws[k][tx << 2];
            float av[4] = {a4.x, a4.y, a4.z, a4.w};
            float bv[4] = {b4.x, b4.y, b4.z, b4.w};
            #pragma unroll
            for (int i = 0; i < 4; ++i)
                #pragma unroll
                for (int j = 0; j < 4; ++j)
                    acc[i][j] = fmaf(av[i], bv[j], acc[i][j]);
        }
        __syncthreads();
    }

    if (z < 2) {
        unsigned short* __restrict__ C = (z == 0) ? Qh : Kh;
        #pragma unroll
        for (int i = 0; i < 4; ++i) {
            ushort4 o;
            o.x = f2h(acc[i][0]); o.y = f2h(acc[i][1]);
            o.z = f2h(acc[i][2]); o.w = f2h(acc[i][3]);
            *(ushort4*)(C + (size_t)(bm + (ty << 2) + i) * 256 + bn + (tx << 2)) = o;
        }
    } else {
        // transpose 64x64 tile in LDS, store bf16 Vt[b][d][k] coalesced
        #pragma unroll
        for (int i = 0; i < 4; ++i)
            #pragma unroll
            for (int j = 0; j < 4; ++j)
                Tt[(tx << 2) + j][(ty << 2) + i] = f2bf(acc[i][j]);
        __syncthreads();
        int dr = t >> 2, kc = (t & 3) << 4;
        int bb = bm >> 10, kin = (bm & 1023) + kc;
        unsigned short* dst = Vt + ((size_t)bb * 256 + bn + dr) * 1024 + kin;
        *(uint4*)(dst + 0) = *(const uint4*)&Tt[dr][kc + 0];
        *(uint4*)(dst + 8) = *(const uint4*)&Tt[dr][kc + 8];
    }
}

// ---------------------------------------------------------------------------
// S-kernel: P[b,q,k] = exp(mask ? Q.K^T : 0) stored bf16, plus partial row
// sums lpart[b,q,16]. fp16 MFMA 16x16x32, BM=BN=128, BK=64, 4 waves (2x2),
// wave tile 64x64 (Mr=Nr=4). global_load_lds w/ pre-swizzled source (T21).
// ---------------------------------------------------------------------------
__global__ __launch_bounds__(256) void s_kernel(
    const unsigned short* __restrict__ Qh, const unsigned short* __restrict__ Kh,
    const int* __restrict__ mask, unsigned short* __restrict__ P,
    float* __restrict__ lpart)
{
    __shared__ unsigned short Asm[2][128 * 64];
    __shared__ unsigned short Bsm[2][128 * 64];

    const int b = blockIdx.z, bm = blockIdx.x << 7, bn = blockIdx.y << 7;
    const int t = threadIdx.x, lane = t & 63, w = t >> 6;
    const int wm = (w >> 1) << 6, wn = (w & 1) << 6;

    const unsigned short* Ag = Qh + ((size_t)b * L_ + bm) * D_;
    const unsigned short* Bg = Kh + ((size_t)b * L_ + bn) * D_;

    f32x4 acc[4][4];
    const f32x4 z4 = {0.f, 0.f, 0.f, 0.f};
    #pragma unroll
    for (int mi = 0; mi < 4; ++mi)
        #pragma unroll
        for (int ni = 0; ni < 4; ++ni) acc[mi][ni] = z4;

    auto stage = [&](int buf, int it) {
        #pragma unroll
        for (int rr = 0; rr < 4; ++rr) {
            int o = (rr << 8) + t;          // 16B-chunk index 0..1023
            int r = o >> 3, c = o & 7;
            int cs = c ^ (r & 7);           // pre-swizzled source chunk
            gl_lds16(Ag + (size_t)r * D_ + (it << 6) + (cs << 3), &Asm[buf][o << 3]);
            gl_lds16(Bg + (size_t)r * D_ + (it << 6) + (cs << 3), &Bsm[buf][o << 3]);
        }
    };

    auto compute = [&](int buf) {
        #pragma unroll
        for (int kc = 0; kc < 2; ++kc) {
            half8 af[4], bfr[4];
            #pragma unroll
            for (int mi = 0; mi < 4; ++mi) {
                int m = wm + (mi << 4) + (lane & 15);
                int cs = ((kc << 2) + (lane >> 4)) ^ (m & 7);
                af[mi] = *(const half8*)&Asm[buf][(m << 6) + (cs << 3)];
            }
            #pragma unroll
            for (int ni = 0; ni < 4; ++ni) {
                int n = wn + (ni << 4) + (lane & 15);
                int cs = ((kc << 2) + (lane >> 4)) ^ (n & 7);
                bfr[ni] = *(const half8*)&Bsm[buf][(n << 6) + (cs << 3)];
            }
            #pragma unroll
            for (int mi = 0; mi < 4; ++mi)
                #pragma unroll
                for (int ni = 0; ni < 4; ++ni)
                    acc[mi][ni] = __builtin_amdgcn_mfma_f32_16x16x32_f16(
                        af[mi], bfr[ni], acc[mi][ni], 0, 0, 0);
        }
    };

    stage(0, 0);
    __syncthreads();
    #pragma unroll
    for (int it2 = 0; it2 < 2; ++it2) {
        stage(1, 2 * it2 + 1);
        compute(0);
        __syncthreads();
        if (2 * it2 + 2 < 4) stage(0, 2 * it2 + 2);
        compute(1);
        __syncthreads();
    }

    // epilogue: mask -> exp -> store bf16 P, partial row sums
    const size_t bL = (size_t)b * L_;
    #pragma unroll
    for (int mi = 0; mi < 4; ++mi) {
        int q0m = bm + wm + (mi << 4) + ((lane >> 4) << 2);
        int mv[4];
        #pragma unroll
        for (int r = 0; r < 4; ++r) mv[r] = mask[bL + q0m + r];
        float lp[4] = {0.f, 0.f, 0.f, 0.f};
        #pragma unroll
        for (int ni = 0; ni < 4; ++ni) {
            int k = bn + wn + (ni << 4) + (lane & 15);
            unsigned short* Pp = P + ((bL + q0m) << 10) + k;
            #pragma unroll
            for (int r = 0; r < 4; ++r) {
                float p = mv[r] ? __expf(acc[mi][ni][r]) : 1.0f;
                Pp[(size_t)r << 10] = f2bf(p);
                lp[r] += p;
            }
        }
        #pragma unroll
        for (int r = 0; r < 4; ++r) {
            float v = lp[r];
            v += __shfl_xor(v, 1);
            v += __shfl_xor(v, 2);
            v += __shfl_xor(v, 4);
            v += __shfl_xor(v, 8);
            if ((lane & 15) == 0)
                lpart[((bL + q0m + r) << 4) + (blockIdx.y << 1) + (w & 1)] = v;
        }
    }
}

// ---------------------------------------------------------------------------
// PV-kernel: Out[b,q,d] = (P . V) / l. bf16 MFMA 16x16x32. BM=128 (q),
// BN=128 (d), BK=64 over LK=1024 (16 iters). B operand from Vt[b][d][k].
// ---------------------------------------------------------------------------
__global__ __launch_bounds__(256) void pv_kernel(
    const unsigned short* __restrict__ P, const unsigned short* __restrict__ Vt,
    const float* __restrict__ lpart, float* __restrict__ Out)
{
    __shared__ unsigned short Asm[2][128 * 64];
    __shared__ unsigned short Bsm[2][128 * 64];

    const int b = blockIdx.z, bm = blockIdx.x << 7, bn = blockIdx.y << 7;
    const int t = threadIdx.x, lane = t & 63, w = t >> 6;
    const int wm = (w >> 1) << 6, wn = (w & 1) << 6;

    const unsigned short* Ag = P  + ((size_t)b << 20) + ((size_t)bm << 10);
    const unsigned short* Bg = Vt + ((size_t)b << 18) + ((size_t)bn << 10);

    f32x4 acc[4][4];
    const f32x4 z4 = {0.f, 0.f, 0.f, 0.f};
    #pragma unroll
    for (int mi = 0; mi < 4; ++mi)
        #pragma unroll
        for (int ni = 0; ni < 4; ++ni) acc[mi][ni] = z4;

    auto stage = [&](int buf, int it) {
        #pragma unroll
        for (int rr = 0; rr < 4; ++rr) {
            int o = (rr << 8) + t;
            int r = o >> 3, c = o & 7;
            int cs = c ^ (r & 7);
            gl_lds16(Ag + ((size_t)r << 10) + (it << 6) + (cs << 3), &Asm[buf][o << 3]);
            gl_lds16(Bg + ((size_t)r << 10) + (it << 6) + (cs << 3), &Bsm[buf][o << 3]);
        }
    };

    auto compute = [&](int buf) {
        #pragma unroll
        for (int kc = 0; kc < 2; ++kc) {
            s16x8 af[4], bfr[4];
            #pragma unroll
            for (int mi = 0; mi < 4; ++mi) {
                int m = wm + (mi << 4) + (lane & 15);
                int cs = ((kc << 2) + (lane >> 4)) ^ (m & 7);
                af[mi] = *(const s16x8*)&Asm[buf][(m << 6) + (cs << 3)];
            }
            #pragma unroll
            for (int ni = 0; ni < 4; ++ni) {
                int n = wn + (ni << 4) + (lane & 15);
                int cs = ((kc << 2) + (lane >> 4)) ^ (n & 7);
                bfr[ni] = *(const s16x8*)&Bsm[buf][(n << 6) + (cs << 3)];
            }
            #pragma unroll
            for (int mi = 0; mi < 4; ++mi)
                #pragma unroll
                for (int ni = 0; ni < 4; ++ni)
                    acc[mi][ni] = __builtin_amdgcn_mfma_f32_16x16x32_bf16(
                        af[mi], bfr[ni], acc[mi][ni], 0, 0, 0);
        }
    };

    stage(0, 0);
    __syncthreads();
    for (int it2 = 0; it2 < 8; ++it2) {
        stage(1, 2 * it2 + 1);
        compute(0);
        __syncthreads();
        if (2 * it2 + 2 < 16) stage(0, 2 * it2 + 2);
        compute(1);
        __syncthreads();
    }

    const size_t bL = (size_t)b * L_;
    #pragma unroll
    for (int mi = 0; mi < 4; ++mi) {
        #pragma unroll
        for (int r = 0; r < 4; ++r) {
            int q = bm + wm + (mi << 4) + ((lane >> 4) << 2) + r;
            const float4* lp4 = (const float4*)(lpart + ((bL + q) << 4));
            float4 s0 = lp4[0], s1 = lp4[1], s2 = lp4[2], s3 = lp4[3];
            float ls = s0.x + s0.y + s0.z + s0.w + s1.x + s1.y + s1.z + s1.w +
                       s2.x + s2.y + s2.z + s2.w + s3.x + s3.y + s3.z + s3.w;
            float inv = 1.0f / ls;
            #pragma unroll
            for (int ni = 0; ni < 4; ++ni) {
                int dcol = bn + wn + (ni << 4) + (lane & 15);
                Out[((bL + q) << 8) + dcol] = acc[mi][ni][r] * inv;
            }
        }
    }
}

extern "C" void kernel_launch(void* const* d_in, const int* in_sizes, int n_in,
                              void* d_out, int out_size, void* d_ws, size_t ws_size,
                              hipStream_t stream) {
    const float* rq = (const float*)d_in[0];
    const float* rk = (const float*)d_in[1];
    const float* rv = (const float*)d_in[2];
    const int*   vm = (const int*)d_in[3];
    const float* WQ = (const float*)d_in[4];
    const float* WK = (const float*)d_in[5];
    const float* WV = (const float*)d_in[6];
    float* out = (float*)d_out;

    char* ws = (char*)d_ws;
    unsigned short* Qh = (unsigned short*)(ws);                          // 16 MB fp16 [b*L][D]
    unsigned short* Kh = (unsigned short*)(ws + ((size_t)16 << 20));     // 16 MB fp16 [b*L][D]
    unsigned short* Vt = (unsigned short*)(ws + ((size_t)32 << 20));     // 16 MB bf16 [b][D][LK]
    unsigned short* Pb = (unsigned short*)(ws + ((size_t)48 << 20));     // 64 MB bf16 [b][LQ][LK]
    float*          lp = (float*)(ws + ((size_t)112 << 20));             //  2 MB f32  [b*LQ][16]

    dim3 pg(512, 4, 3);
    proj_kernel<<<pg, 256, 0, stream>>>(rq, WQ, rk, WK, rv, WV, Qh, Kh, Vt);

    dim3 sg(8, 8, 32);
    s_kernel<<<sg, 256, 0, stream>>>(Qh, Kh, vm, Pb, lp);

    dim3 vg(8, 2, 32);
    pv_kernel<<<vg, 256, 0, stream>>>(Pb, Vt, lp, out);
}

// Round 4
// 131.370 us; speedup vs baseline: 9.9784x; 1.9955x over previous
//
#include <hip/hip_runtime.h>
#include <hip/hip_bf16.h>
#include <math.h>

#define B_ 32
#define L_ 1024
#define D_ 256

typedef _Float16 half8 __attribute__((ext_vector_type(8)));
typedef __fp16   fp16x2 __attribute__((ext_vector_type(2)));
typedef short    s16x8 __attribute__((ext_vector_type(8)));
typedef float    f32x4 __attribute__((ext_vector_type(4)));

typedef __attribute__((address_space(3))) unsigned int lds_u32;
typedef __attribute__((address_space(1))) unsigned int gbl_u32;

__device__ __forceinline__ void gl_lds16(const void* g, void* l) {
    __builtin_amdgcn_global_load_lds((gbl_u32*)g, (lds_u32*)l, 16, 0, 0);
}

__device__ __forceinline__ unsigned short f2bf(float x) {
    unsigned u = __float_as_uint(x);
    u += 0x7FFFu + ((u >> 16) & 1u);
    return (unsigned short)(u >> 16);
}

__device__ __forceinline__ unsigned short f2h(float x) {
    _Float16 h = (_Float16)x;
    unsigned short u;
    __builtin_memcpy(&u, &h, 2);
    return u;
}

__device__ __forceinline__ unsigned pkrtz(float a, float b) {
    fp16x2 v = __builtin_amdgcn_cvt_pkrtz(a, b);
    unsigned u;
    __builtin_memcpy(&u, &v, 4);
    return u;
}

// ---------------------------------------------------------------------------
// W-prep: Wt[z][n][k] = fp16(W[z][k][n]) via LDS 64x64 tile transpose.
// ---------------------------------------------------------------------------
__global__ __launch_bounds__(256) void wprep_kernel(
    const float* __restrict__ W0, const float* __restrict__ W1,
    const float* __restrict__ W2, unsigned short* __restrict__ Wt)
{
    const int z = blockIdx.z;
    const float* __restrict__ W = (z == 0) ? W0 : (z == 1) ? W1 : W2;
    __shared__ unsigned short T[64][72];
    const int k0 = blockIdx.x << 6, n0 = blockIdx.y << 6;
    const int t = threadIdx.x;
    const int r = t >> 2, c0 = (t & 3) << 4;
    #pragma unroll
    for (int j = 0; j < 16; j += 4) {
        float4 w4 = *(const float4*)(W + (size_t)(k0 + r) * 256 + n0 + c0 + j);
        T[c0 + j + 0][r] = f2h(w4.x);
        T[c0 + j + 1][r] = f2h(w4.y);
        T[c0 + j + 2][r] = f2h(w4.z);
        T[c0 + j + 3][r] = f2h(w4.w);
    }
    __syncthreads();
    const int n = t >> 2, kc = (t & 3) << 4;
    unsigned short* dst = Wt + ((size_t)z << 16) + (size_t)(n0 + n) * 256 + k0 + kc;
    *(uint4*)(dst + 0) = *(const uint4*)&T[n][kc + 0];
    *(uint4*)(dst + 8) = *(const uint4*)&T[n][kc + 8];
}

// ---------------------------------------------------------------------------
// Projection GEMM, fp16 MFMA 16x16x32. C[M=32768,256] = A @ W.
// BM=128, BN=128 (grid y=2), BK=64, 4 waves 2x2, wave tile 64x64.
// A: raw fp32 -> cvt_pkrtz -> swizzled ds_write. B: Wt fp16 via gl_lds.
// z<2: store fp16 row-major. z=2: LDS-transpose -> Vt bf16 [b][d][k].
// ---------------------------------------------------------------------------
__global__ __launch_bounds__(256) void proj_mfma_kernel(
    const float* __restrict__ A0, const float* __restrict__ A1,
    const float* __restrict__ A2, const unsigned short* __restrict__ Wt,
    unsigned short* __restrict__ Qh, unsigned short* __restrict__ Kh,
    unsigned short* __restrict__ Vt)
{
    __shared__ unsigned short SMEM[32768];   // 64 KB: A dbuf 16Kx2, B dbuf 16Kx2
    unsigned short* Asm = SMEM;              // [buf][128*64], buf stride 8192
    unsigned short* Bsm = SMEM + 16384;

    const int z = blockIdx.z;
    const float* __restrict__ A = (z == 0) ? A0 : (z == 1) ? A1 : A2;
    const int bm = blockIdx.x << 7, bn = blockIdx.y << 7;
    const int t = threadIdx.x, lane = t & 63, w = t >> 6;
    const int wm = (w >> 1) << 6, wn = (w & 1) << 6;

    const float* __restrict__ Ag = A + (size_t)bm * 256;
    const unsigned short* __restrict__ Bg = Wt + ((size_t)z << 16) + (size_t)bn * 256;

    f32x4 acc[4][4];
    const f32x4 z4 = {0.f, 0.f, 0.f, 0.f};
    #pragma unroll
    for (int mi = 0; mi < 4; ++mi)
        #pragma unroll
        for (int ni = 0; ni < 4; ++ni) acc[mi][ni] = z4;

    auto stageB = [&](int buf, int it) {
        #pragma unroll
        for (int rr = 0; rr < 4; ++rr) {
            int o = (rr << 8) + t;          // 0..1023
            int r = o >> 3, c = o & 7;
            int cs = c ^ (r & 7);
            gl_lds16(Bg + (size_t)r * 256 + (it << 6) + (cs << 3),
                     &Bsm[(buf << 13) + (o << 3)]);
        }
    };

    auto stageA = [&](int buf, int it) {
        #pragma unroll
        for (int i = 0; i < 8; ++i) {
            int r  = (t >> 4) + (i << 4);    // 0..127
            int c4 = t & 15;                 // float4 index within 64 floats
            float4 a4 = *(const float4*)(Ag + (size_t)r * 256 + (it << 6) + (c4 << 2));
            unsigned h01 = pkrtz(a4.x, a4.y);
            unsigned h23 = pkrtz(a4.z, a4.w);
            int c  = c4 >> 1;
            int cs = c ^ (r & 7);
            uint2 d2;
            d2.x = h01; d2.y = h23;
            *(uint2*)&Asm[(buf << 13) + (r << 6) + (cs << 3) + ((c4 & 1) << 2)] = d2;
        }
    };

    auto compute = [&](int buf) {
        #pragma unroll
        for (int kc = 0; kc < 2; ++kc) {
            half8 af[4], bfr[4];
            #pragma unroll
            for (int mi = 0; mi < 4; ++mi) {
                int m = wm + (mi << 4) + (lane & 15);
                int cs = ((kc << 2) + (lane >> 4)) ^ (m & 7);
                af[mi] = *(const half8*)&Asm[(buf << 13) + (m << 6) + (cs << 3)];
            }
            #pragma unroll
            for (int ni = 0; ni < 4; ++ni) {
                int n = wn + (ni << 4) + (lane & 15);
                int cs = ((kc << 2) + (lane >> 4)) ^ (n & 7);
                bfr[ni] = *(const half8*)&Bsm[(buf << 13) + (n << 6) + (cs << 3)];
            }
            #pragma unroll
            for (int mi = 0; mi < 4; ++mi)
                #pragma unroll
                for (int ni = 0; ni < 4; ++ni)
                    acc[mi][ni] = __builtin_amdgcn_mfma_f32_16x16x32_f16(
                        af[mi], bfr[ni], acc[mi][ni], 0, 0, 0);
        }
    };

    stageA(0, 0); stageB(0, 0);
    __syncthreads();
    stageA(1, 1); stageB(1, 1);
    compute(0);
    __syncthreads();
    stageA(0, 2); stageB(0, 2);
    compute(1);
    __syncthreads();
    stageA(1, 3); stageB(1, 3);
    compute(0);
    __syncthreads();
    compute(1);

    if (z < 2) {
        unsigned short* __restrict__ C = (z == 0) ? Qh : Kh;
        #pragma unroll
        for (int mi = 0; mi < 4; ++mi) {
            int q = bm + wm + (mi << 4) + ((lane >> 4) << 2);
            #pragma unroll
            for (int ni = 0; ni < 4; ++ni) {
                int col = bn + wn + (ni << 4) + (lane & 15);
                #pragma unroll
                for (int r = 0; r < 4; ++r)
                    C[(size_t)(q + r) * 256 + col] = f2h(acc[mi][ni][r]);
            }
        }
    } else {
        __syncthreads();
        unsigned short (*Tt)[144] = (unsigned short(*)[144])SMEM;  // 128x144 = 36 KB
        #pragma unroll
        for (int mi = 0; mi < 4; ++mi) {
            #pragma unroll
            for (int ni = 0; ni < 4; ++ni) {
                int n  = wn + (ni << 4) + (lane & 15);
                int m0 = wm + (mi << 4) + ((lane >> 4) << 2);
                ushort4 v;
                v.x = f2bf(acc[mi][ni][0]);
                v.y = f2bf(acc[mi][ni][1]);
                v.z = f2bf(acc[mi][ni][2]);
                v.w = f2bf(acc[mi][ni][3]);
                *(ushort4*)&Tt[n][m0] = v;
            }
        }
        __syncthreads();
        const int bb = bm >> 10, kin = bm & 1023;
        const int dr = t >> 1, cb = (t & 1) << 6;
        unsigned short* dst = Vt + ((size_t)bb * 256 + bn + dr) * 1024 + kin + cb;
        #pragma unroll
        for (int j = 0; j < 8; ++j)
            *(uint4*)(dst + (j << 3)) = *(const uint4*)&Tt[dr][cb + (j << 3)];
    }
}

// ---------------------------------------------------------------------------
// S-kernel: P[b,q,k] = exp(mask ? Q.K^T : 0) bf16, + partial row sums.
// ---------------------------------------------------------------------------
__global__ __launch_bounds__(256) void s_kernel(
    const unsigned short* __restrict__ Qh, const unsigned short* __restrict__ Kh,
    const int* __restrict__ mask, unsigned short* __restrict__ P,
    float* __restrict__ lpart)
{
    __shared__ unsigned short Asm[2][128 * 64];
    __shared__ unsigned short Bsm[2][128 * 64];

    const int b = blockIdx.z, bm = blockIdx.x << 7, bn = blockIdx.y << 7;
    const int t = threadIdx.x, lane = t & 63, w = t >> 6;
    const int wm = (w >> 1) << 6, wn = (w & 1) << 6;

    const unsigned short* Ag = Qh + ((size_t)b * L_ + bm) * D_;
    const unsigned short* Bg = Kh + ((size_t)b * L_ + bn) * D_;

    f32x4 acc[4][4];
    const f32x4 z4 = {0.f, 0.f, 0.f, 0.f};
    #pragma unroll
    for (int mi = 0; mi < 4; ++mi)
        #pragma unroll
        for (int ni = 0; ni < 4; ++ni) acc[mi][ni] = z4;

    auto stage = [&](int buf, int it) {
        #pragma unroll
        for (int rr = 0; rr < 4; ++rr) {
            int o = (rr << 8) + t;
            int r = o >> 3, c = o & 7;
            int cs = c ^ (r & 7);
            gl_lds16(Ag + (size_t)r * D_ + (it << 6) + (cs << 3), &Asm[buf][o << 3]);
            gl_lds16(Bg + (size_t)r * D_ + (it << 6) + (cs << 3), &Bsm[buf][o << 3]);
        }
    };

    auto compute = [&](int buf) {
        #pragma unroll
        for (int kc = 0; kc < 2; ++kc) {
            half8 af[4], bfr[4];
            #pragma unroll
            for (int mi = 0; mi < 4; ++mi) {
                int m = wm + (mi << 4) + (lane & 15);
                int cs = ((kc << 2) + (lane >> 4)) ^ (m & 7);
                af[mi] = *(const half8*)&Asm[buf][(m << 6) + (cs << 3)];
            }
            #pragma unroll
            for (int ni = 0; ni < 4; ++ni) {
                int n = wn + (ni << 4) + (lane & 15);
                int cs = ((kc << 2) + (lane >> 4)) ^ (n & 7);
                bfr[ni] = *(const half8*)&Bsm[buf][(n << 6) + (cs << 3)];
            }
            #pragma unroll
            for (int mi = 0; mi < 4; ++mi)
                #pragma unroll
                for (int ni = 0; ni < 4; ++ni)
                    acc[mi][ni] = __builtin_amdgcn_mfma_f32_16x16x32_f16(
                        af[mi], bfr[ni], acc[mi][ni], 0, 0, 0);
        }
    };

    stage(0, 0);
    __syncthreads();
    #pragma unroll
    for (int it2 = 0; it2 < 2; ++it2) {
        stage(1, 2 * it2 + 1);
        compute(0);
        __syncthreads();
        if (2 * it2 + 2 < 4) stage(0, 2 * it2 + 2);
        compute(1);
        __syncthreads();
    }

    const size_t bL = (size_t)b * L_;
    #pragma unroll
    for (int mi = 0; mi < 4; ++mi) {
        int q0m = bm + wm + (mi << 4) + ((lane >> 4) << 2);
        int mv[4];
        #pragma unroll
        for (int r = 0; r < 4; ++r) mv[r] = mask[bL + q0m + r];
        float lp[4] = {0.f, 0.f, 0.f, 0.f};
        #pragma unroll
        for (int ni = 0; ni < 4; ++ni) {
            int k = bn + wn + (ni << 4) + (lane & 15);
            unsigned short* Pp = P + ((bL + q0m) << 10) + k;
            #pragma unroll
            for (int r = 0; r < 4; ++r) {
                float p = mv[r] ? __expf(acc[mi][ni][r]) : 1.0f;
                Pp[(size_t)r << 10] = f2bf(p);
                lp[r] += p;
            }
        }
        #pragma unroll
        for (int r = 0; r < 4; ++r) {
            float v = lp[r];
            v += __shfl_xor(v, 1);
            v += __shfl_xor(v, 2);
            v += __shfl_xor(v, 4);
            v += __shfl_xor(v, 8);
            if ((lane & 15) == 0)
                lpart[((bL + q0m + r) << 4) + (blockIdx.y << 1) + (w & 1)] = v;
        }
    }
}

// ---------------------------------------------------------------------------
// PV-kernel: Out[b,q,d] = (P . V) / l, bf16 MFMA.
// ---------------------------------------------------------------------------
__global__ __launch_bounds__(256) void pv_kernel(
    const unsigned short* __restrict__ P, const unsigned short* __restrict__ Vt,
    const float* __restrict__ lpart, float* __restrict__ Out)
{
    __shared__ unsigned short Asm[2][128 * 64];
    __shared__ unsigned short Bsm[2][128 * 64];

    const int b = blockIdx.z, bm = blockIdx.x << 7, bn = blockIdx.y << 7;
    const int t = threadIdx.x, lane = t & 63, w = t >> 6;
    const int wm = (w >> 1) << 6, wn = (w & 1) << 6;

    const unsigned short* Ag = P  + ((size_t)b << 20) + ((size_t)bm << 10);
    const unsigned short* Bg = Vt + ((size_t)b << 18) + ((size_t)bn << 10);

    f32x4 acc[4][4];
    const f32x4 z4 = {0.f, 0.f, 0.f, 0.f};
    #pragma unroll
    for (int mi = 0; mi < 4; ++mi)
        #pragma unroll
        for (int ni = 0; ni < 4; ++ni) acc[mi][ni] = z4;

    auto stage = [&](int buf, int it) {
        #pragma unroll
        for (int rr = 0; rr < 4; ++rr) {
            int o = (rr << 8) + t;
            int r = o >> 3, c = o & 7;
            int cs = c ^ (r & 7);
            gl_lds16(Ag + ((size_t)r << 10) + (it << 6) + (cs << 3), &Asm[buf][o << 3]);
            gl_lds16(Bg + ((size_t)r << 10) + (it << 6) + (cs << 3), &Bsm[buf][o << 3]);
        }
    };

    auto compute = [&](int buf) {
        #pragma unroll
        for (int kc = 0; kc < 2; ++kc) {
            s16x8 af[4], bfr[4];
            #pragma unroll
            for (int mi = 0; mi < 4; ++mi) {
                int m = wm + (mi << 4) + (lane & 15);
                int cs = ((kc << 2) + (lane >> 4)) ^ (m & 7);
                af[mi] = *(const s16x8*)&Asm[buf][(m << 6) + (cs << 3)];
            }
            #pragma unroll
            for (int ni = 0; ni < 4; ++ni) {
                int n = wn + (ni << 4) + (lane & 15);
                int cs = ((kc << 2) + (lane >> 4)) ^ (n & 7);
                bfr[ni] = *(const s16x8*)&Bsm[buf][(n << 6) + (cs << 3)];
            }
            #pragma unroll
            for (int mi = 0; mi < 4; ++mi)
                #pragma unroll
                for (int ni = 0; ni < 4; ++ni)
                    acc[mi][ni] = __builtin_amdgcn_mfma_f32_16x16x32_bf16(
                        af[mi], bfr[ni], acc[mi][ni], 0, 0, 0);
        }
    };

    stage(0, 0);
    __syncthreads();
    for (int it2 = 0; it2 < 8; ++it2) {
        stage(1, 2 * it2 + 1);
        compute(0);
        __syncthreads();
        if (2 * it2 + 2 < 16) stage(0, 2 * it2 + 2);
        compute(1);
        __syncthreads();
    }

    const size_t bL = (size_t)b * L_;
    #pragma unroll
    for (int mi = 0; mi < 4; ++mi) {
        #pragma unroll
        for (int r = 0; r < 4; ++r) {
            int q = bm + wm + (mi << 4) + ((lane >> 4) << 2) + r;
            const float4* lp4 = (const float4*)(lpart + ((bL + q) << 4));
            float4 s0 = lp4[0], s1 = lp4[1], s2 = lp4[2], s3 = lp4[3];
            float ls = s0.x + s0.y + s0.z + s0.w + s1.x + s1.y + s1.z + s1.w +
                       s2.x + s2.y + s2.z + s2.w + s3.x + s3.y + s3.z + s3.w;
            float inv = 1.0f / ls;
            #pragma unroll
            for (int ni = 0; ni < 4; ++ni) {
                int dcol = bn + wn + (ni << 4) + (lane & 15);
                Out[((bL + q) << 8) + dcol] = acc[mi][ni][r] * inv;
            }
        }
    }
}

extern "C" void kernel_launch(void* const* d_in, const int* in_sizes, int n_in,
                              void* d_out, int out_size, void* d_ws, size_t ws_size,
                              hipStream_t stream) {
    const float* rq = (const float*)d_in[0];
    const float* rk = (const float*)d_in[1];
    const float* rv = (const float*)d_in[2];
    const int*   vm = (const int*)d_in[3];
    const float* WQ = (const float*)d_in[4];
    const float* WK = (const float*)d_in[5];
    const float* WV = (const float*)d_in[6];
    float* out = (float*)d_out;

    char* ws = (char*)d_ws;
    unsigned short* Qh = (unsigned short*)(ws);                          // 16 MB fp16 [b*L][D]
    unsigned short* Kh = (unsigned short*)(ws + ((size_t)16 << 20));     // 16 MB fp16 [b*L][D]
    unsigned short* Vt = (unsigned short*)(ws + ((size_t)32 << 20));     // 16 MB bf16 [b][D][LK]
    unsigned short* Pb = (unsigned short*)(ws + ((size_t)48 << 20));     // 64 MB bf16 [b][LQ][LK]
    float*          lp = (float*)(ws + ((size_t)112 << 20));             //  2 MB f32  [b*LQ][16]
    // Wt lives at the start of the Pb region: consumed by proj_mfma BEFORE
    // s_kernel writes Pb (same-stream ordering); rewritten every replay.
    unsigned short* Wt = Pb;                                             // 384 KB fp16 [3][256][256]

    dim3 wg(4, 4, 3);
    wprep_kernel<<<wg, 256, 0, stream>>>(WQ, WK, WV, Wt);

    dim3 pg(256, 2, 3);
    proj_mfma_kernel<<<pg, 256, 0, stream>>>(rq, rk, rv, Wt, Qh, Kh, Vt);

    dim3 sg(8, 8, 32);
    s_kernel<<<sg, 256, 0, stream>>>(Qh, Kh, vm, Pb, lp);

    dim3 vg(8, 2, 32);
    pv_kernel<<<vg, 256, 0, stream>>>(Pb, Vt, lp, out);
}